// Round 5
// baseline (185.727 us; speedup 1.0000x reference)
//
#include <hip/hip_runtime.h>
#include <stdint.h>

#define B_SZ 4096
#define D_K  2048   // D_IN + D_H
#define DH   1024

#define BM   256    // M rows per block
#define BN_H 32     // h columns per block (x4 gates = 128 N columns)
#define BKI  128    // i8 K elements per LDS tile (2 MFMA k64-steps)
#define NIT  (D_K / BKI)  // 16 K-iterations (must be even)

typedef __attribute__((ext_vector_type(4))) int intx4;

__device__ __forceinline__ float fast_sigmoid(float x) {
  return 1.0f / (1.0f + __expf(-x));
}
__device__ __forceinline__ float fast_tanh(float x) {
  return 2.0f / (1.0f + __expf(-2.0f * x)) - 1.0f;
}

#define SQRT2048 45.254833995939045f   // s = 1/sqrt(D_IN+D_H), exact init bound

// Per-row i8 quantization.
//  Blocks 0..4095:    A row m: a = [x[m] | h[m]]; scale = rowmax/127 (stored in sA)
//  Blocks 4096..8191: W row n (gate-major): w bounded by s=1/sqrt(2048) exactly
//                     -> constant scale s/127, no reduction needed.
// Each thread: 8 fp32 -> 8 i8 packed as uint2. Fully coalesced.
__global__ __launch_bounds__(256) void prep_i8(
    const float* __restrict__ xin, const float* __restrict__ hprev,
    const float* __restrict__ Wi, const float* __restrict__ Wf,
    const float* __restrict__ Wc, const float* __restrict__ Wo,
    int8_t* __restrict__ Ai8, int8_t* __restrict__ Wq8,
    float* __restrict__ sA)
{
  __shared__ float wm[4];
  const int r = blockIdx.x;
  const int t = threadIdx.x;
  const int k = t * 8;
  float v[8];

  if (r < B_SZ) {
    const int m = r;
    const float* src = (k < 1024) ? (xin + (size_t)m * 1024 + k)
                                  : (hprev + (size_t)m * 1024 + (k - 1024));
    float4 f0 = *(const float4*)src;
    float4 f1 = *(const float4*)(src + 4);
    v[0]=f0.x; v[1]=f0.y; v[2]=f0.z; v[3]=f0.w;
    v[4]=f1.x; v[5]=f1.y; v[6]=f1.z; v[7]=f1.w;
    float lm = 0.f;
    #pragma unroll
    for (int j = 0; j < 8; ++j) lm = fmaxf(lm, fabsf(v[j]));
    #pragma unroll
    for (int mask = 32; mask >= 1; mask >>= 1)
      lm = fmaxf(lm, __shfl_xor(lm, mask, 64));
    const int wave = t >> 6, lane = t & 63;
    if (lane == 0) wm[wave] = lm;
    __syncthreads();
    float rowmax = fmaxf(fmaxf(wm[0], wm[1]), fmaxf(wm[2], wm[3]));
    rowmax = fmaxf(rowmax, 1e-20f);
    if (t == 0) sA[m] = rowmax * (1.0f / 127.0f);
    const float qs = 127.0f / rowmax;
    uint32_t lo = 0, hi = 0;
    #pragma unroll
    for (int j = 0; j < 4; ++j) {
      int q = __float2int_rn(v[j] * qs);
      lo |= (uint32_t)(q & 255) << (8 * j);
    }
    #pragma unroll
    for (int j = 0; j < 4; ++j) {
      int q = __float2int_rn(v[4 + j] * qs);
      hi |= (uint32_t)(q & 255) << (8 * j);
    }
    uint2 out; out.x = lo; out.y = hi;
    *(uint2*)(Ai8 + (size_t)m * D_K + k) = out;
  } else {
    const int n = r - B_SZ;
    const int g = n >> 10, h = n & 1023;
    const float* wsrc = (g == 0) ? Wi : (g == 1) ? Wf : (g == 2) ? Wc : Wo;
    const float* src = wsrc + (size_t)h * D_K + k;
    float4 f0 = *(const float4*)src;
    float4 f1 = *(const float4*)(src + 4);
    v[0]=f0.x; v[1]=f0.y; v[2]=f0.z; v[3]=f0.w;
    v[4]=f1.x; v[5]=f1.y; v[6]=f1.z; v[7]=f1.w;
    const float qs = 127.0f * SQRT2048;   // 127/s
    uint32_t lo = 0, hi = 0;
    #pragma unroll
    for (int j = 0; j < 4; ++j) {
      int q = min(127, max(-127, __float2int_rn(v[j] * qs)));
      lo |= (uint32_t)(q & 255) << (8 * j);
    }
    #pragma unroll
    for (int j = 0; j < 4; ++j) {
      int q = min(127, max(-127, __float2int_rn(v[4 + j] * qs)));
      hi |= (uint32_t)(q & 255) << (8 * j);
    }
    uint2 out; out.x = lo; out.y = hi;
    *(uint2*)(Wq8 + (size_t)n * D_K + k) = out;
  }
}

// Fused i8 GEMM + LSTM epilogue — counted-vmcnt pipeline (T3+T4+T5 port):
//  * BM=256, 512 threads = 8 waves (4 M-quarters x 2 h-halves); each wave
//    owns 64M x (4 gates x 16h) = 4x4 frags of 16x16x64_i8 (exact i32 acc).
//  * Double-buffered LDS: 2 x (32KB A + 16KB B) = 96 KB -> 1 block/CU.
//  * Per K-iter: issue 6 global_load_lds for tile kt+1, then
//    s_waitcnt vmcnt(6)  (waits ONLY for tile kt's 6 loads; next tile's
//    stay in flight across the barrier), s_barrier, MFMA phase (setprio 1),
//    s_barrier (read-done before the buffer is overwritten next iter).
//    No vmcnt(0) drain in the main loop — the m218/m201 counted-wait lever.
//  * Epilogue global loads sit after the final memory-clobber asm so the
//    compiler cannot hoist them into the counted-vmcnt region.
// Bank swizzle (verified): row r's logical 16B chunk c at physical c^(r&7);
// staging realizes it by permuting the global SOURCE chunk (HW forces
// LDS dst = wavebase + lane*16). Any k-permutation cancels between the
// identically-laid-out A and B operands; C/D layout is dtype-independent.
__global__ __launch_bounds__(512, 1) void lstm_gemm_i8(
    const int8_t* __restrict__ A,   // [4096][2048] i8
    const int8_t* __restrict__ W,   // [4096][2048] i8 gate-major
    const float* __restrict__ sA,   // [4096] per-row A scale
    const float* __restrict__ bi, const float* __restrict__ bfv,
    const float* __restrict__ bc, const float* __restrict__ bo,
    const float* __restrict__ cprev,
    float* __restrict__ out)        // [h_next | c_next] fp32
{
  __shared__ __align__(16) int8_t lA[2][BM * BKI];   // 2 x 32 KB
  __shared__ __align__(16) int8_t lB[2][128 * BKI];  // 2 x 16 KB

  const int m0 = blockIdx.x * BM;
  const int h0 = blockIdx.y * BN_H;
  const int tid = threadIdx.x;
  const int wave = tid >> 6;   // 0..7
  const int lane = tid & 63;
  const int wm = wave >> 1;    // M quarter (64 rows)
  const int wn = wave & 1;     // h half (16 cols)

  // ---- staging: one instr = 64 lanes x 16B = 8 rows of 128B
  const int sr8 = lane >> 3;          // row within 8-row group
  const int sch = lane & 7;           // physical 16B chunk (forced by HW)
  const int gc  = sch ^ sr8;          // swizzled global source chunk (key=row&7)

  // A tile: 256 rows; 8 waves x 4 instrs x 8 rows
  const int8_t* aSrc[4];
  int dOffA[4];
  #pragma unroll
  for (int j = 0; j < 4; ++j) {
    int r = wave * 32 + j * 8 + sr8;         // 0..255, r&7 == sr8
    aSrc[j] = A + (size_t)(m0 + r) * D_K + gc * 16;
    dOffA[j] = r * BKI + sch * 16;
  }
  // B tile: 128 rows (gate-major); 8 waves x 2 instrs x 8 rows
  const int8_t* bSrc[2];
  int dOffB[2];
  #pragma unroll
  for (int j = 0; j < 2; ++j) {
    int r = wave * 16 + j * 8 + sr8;         // 0..127, r&7 == sr8
    bSrc[j] = W + (size_t)((r >> 5) * DH + h0 + (r & 31)) * D_K + gc * 16;
    dOffB[j] = r * BKI + sch * 16;
  }

  intx4 acc[4][4];
  #pragma unroll
  for (int i = 0; i < 4; ++i)
    #pragma unroll
    for (int j = 0; j < 4; ++j)
      acc[i][j] = (intx4){0, 0, 0, 0};

  // ---- fragment reads: frag row = base + fr; logical chunk kk*4+q
  const int fr = lane & 15;
  const int q  = lane >> 4;
  const int cx0 = ((q + 0) ^ (fr & 7)) * 16;   // kk=0
  const int cx1 = ((q + 4) ^ (fr & 7)) * 16;   // kk=1

#define STAGE(buf, kt) do {                                                  \
    const int _ko = (kt) * BKI;                                              \
    _Pragma("unroll")                                                        \
    for (int j = 0; j < 4; ++j)                                              \
      __builtin_amdgcn_global_load_lds(                                      \
          (const __attribute__((address_space(1))) void*)(aSrc[j] + _ko),    \
          (__attribute__((address_space(3))) void*)&lA[buf][dOffA[j]], 16, 0, 0); \
    _Pragma("unroll")                                                        \
    for (int j = 0; j < 2; ++j)                                              \
      __builtin_amdgcn_global_load_lds(                                      \
          (const __attribute__((address_space(1))) void*)(bSrc[j] + _ko),    \
          (__attribute__((address_space(3))) void*)&lB[buf][dOffB[j]], 16, 0, 0); \
  } while (0)

#define COMPUTE(buf) do {                                                    \
    _Pragma("unroll")                                                        \
    for (int kk = 0; kk < 2; ++kk) {                                         \
      const int cx = kk ? cx1 : cx0;                                         \
      intx4 bq[4];                                                           \
      _Pragma("unroll")                                                      \
      for (int g = 0; g < 4; ++g)                                            \
        bq[g] = *(const intx4*)&lB[buf][(g * 32 + wn * 16 + fr) * BKI + cx]; \
      __builtin_amdgcn_s_setprio(1);                                         \
      _Pragma("unroll")                                                      \
      for (int i = 0; i < 4; ++i) {                                          \
        intx4 aq = *(const intx4*)&lA[buf][(wm * 64 + i * 16 + fr) * BKI + cx]; \
        acc[i][0] = __builtin_amdgcn_mfma_i32_16x16x64_i8(aq, bq[0], acc[i][0], 0, 0, 0); \
        acc[i][1] = __builtin_amdgcn_mfma_i32_16x16x64_i8(aq, bq[1], acc[i][1], 0, 0, 0); \
        acc[i][2] = __builtin_amdgcn_mfma_i32_16x16x64_i8(aq, bq[2], acc[i][2], 0, 0, 0); \
        acc[i][3] = __builtin_amdgcn_mfma_i32_16x16x64_i8(aq, bq[3], acc[i][3], 0, 0, 0); \
      }                                                                      \
      __builtin_amdgcn_s_setprio(0);                                         \
    }                                                                        \
  } while (0)

  // Prologue: stage tile 0; no drain — iter 0's vmcnt(6) covers it.
  STAGE(0, 0);

  #pragma unroll 1
  for (int kt = 0; kt < NIT; kt += 2) {
    // ---- even iter: compute buf0 (tile kt)
    STAGE(1, kt + 1);                              // kt+1 <= 15 always
    asm volatile("s_waitcnt vmcnt(6)" ::: "memory");  // tile kt resident
    __builtin_amdgcn_s_barrier();
    COMPUTE(0);
    __builtin_amdgcn_s_barrier();                  // all reads of buf0 done
    // ---- odd iter: compute buf1 (tile kt+1)
    if (kt + 2 < NIT) {
      STAGE(0, kt + 2);
      asm volatile("s_waitcnt vmcnt(6)" ::: "memory");
    } else {
      asm volatile("s_waitcnt vmcnt(0)" ::: "memory");  // final tile drain
    }
    __builtin_amdgcn_s_barrier();
    COMPUTE(1);
    __builtin_amdgcn_s_barrier();
  }

#undef STAGE
#undef COMPUTE

  // Epilogue: C/D layout col=lane&15, row=(lane>>4)*4+reg (dtype-independent).
  // z = acc_i32 * (sA[m] * s/127) + bias
  const int col = lane & 15;
  const int rq = lane >> 4;
  const int h = h0 + wn * 16 + col;
  const float sWc = (1.0f / SQRT2048) * (1.0f / 127.0f);   // s/127
  const float bias_i = bi[h], bias_f = bfv[h], bias_c = bc[h], bias_o = bo[h];
  float* hout = out;
  float* cout = out + (size_t)B_SZ * DH;
  #pragma unroll
  for (int i = 0; i < 4; ++i) {
    int mb = m0 + wm * 64 + i * 16 + rq * 4;
    #pragma unroll
    for (int r = 0; r < 4; ++r) {
      int m = mb + r;
      float fz = sA[m] * sWc;
      float zi = (float)acc[i][0][r] * fz + bias_i;
      float zf = (float)acc[i][1][r] * fz + bias_f;
      float zc = (float)acc[i][2][r] * fz + bias_c;
      float zo = (float)acc[i][3][r] * fz + bias_o;
      float ig = fast_sigmoid(zi);
      float fg = fast_sigmoid(zf);
      float cg = fast_tanh(zc);
      float og = fast_sigmoid(zo);
      float cp = cprev[(size_t)m * DH + h];
      float cn = fg * cp + ig * cg;
      float hn = og * fast_tanh(cn);
      hout[(size_t)m * DH + h] = hn;
      cout[(size_t)m * DH + h] = cn;
    }
  }
}

extern "C" void kernel_launch(void* const* d_in, const int* in_sizes, int n_in,
                              void* d_out, int out_size, void* d_ws, size_t ws_size,
                              hipStream_t stream)
{
  const float* xin   = (const float*)d_in[0];
  const float* hprev = (const float*)d_in[1];
  const float* cprev = (const float*)d_in[2];
  const float* Wi    = (const float*)d_in[3];
  const float* bi    = (const float*)d_in[4];
  const float* Wf    = (const float*)d_in[5];
  const float* bfv   = (const float*)d_in[6];
  const float* Wc    = (const float*)d_in[7];
  const float* bc    = (const float*)d_in[8];
  const float* Wo    = (const float*)d_in[9];
  const float* bo    = (const float*)d_in[10];
  float* out = (float*)d_out;

  int8_t* Ai8 = (int8_t*)d_ws;                                 // 8 MB
  int8_t* Wq8 = Ai8 + (size_t)B_SZ * D_K;                      // 8 MB
  float*  sA  = (float*)(Wq8 + (size_t)4 * DH * D_K);          // 16 KB

  prep_i8<<<2 * B_SZ, 256, 0, stream>>>(
      xin, hprev, Wi, Wf, Wc, Wo, Ai8, Wq8, sA);

  dim3 grid(B_SZ / BM, DH / BN_H);  // 16 x 32 = 512 blocks
  lstm_gemm_i8<<<grid, 512, 0, stream>>>(
      Ai8, Wq8, sA, bi, bfv, bc, bo, cprev, out);
}

// Round 7
// 173.594 us; speedup vs baseline: 1.0699x; 1.0699x over previous
//
#include <hip/hip_runtime.h>
#include <stdint.h>

#define B_SZ 4096
#define D_K  2048   // D_IN + D_H
#define DH   1024

#define BM   256    // M rows per block
#define BN_H 64     // h columns per block (x4 gates = 256 N columns)
#define BKI  128    // i8 K elements per LDS K-tile (2 MFMA k64-steps)
#define NIT  (D_K / BKI)  // 16 K-tiles

typedef __attribute__((ext_vector_type(4))) int intx4;

__device__ __forceinline__ float fast_sigmoid(float x) {
  return 1.0f / (1.0f + __expf(-x));
}
__device__ __forceinline__ float fast_tanh(float x) {
  return 2.0f / (1.0f + __expf(-2.0f * x)) - 1.0f;
}

#define SQRT2048 45.254833995939045f   // s = 1/sqrt(D_IN+D_H), exact init bound

// Per-row i8 quantization (unchanged, harness-verified).
__global__ __launch_bounds__(256) void prep_i8(
    const float* __restrict__ xin, const float* __restrict__ hprev,
    const float* __restrict__ Wi, const float* __restrict__ Wf,
    const float* __restrict__ Wc, const float* __restrict__ Wo,
    int8_t* __restrict__ Ai8, int8_t* __restrict__ Wq8,
    float* __restrict__ sA)
{
  __shared__ float wm[4];
  const int r = blockIdx.x;
  const int t = threadIdx.x;
  const int k = t * 8;
  float v[8];

  if (r < B_SZ) {
    const int m = r;
    const float* src = (k < 1024) ? (xin + (size_t)m * 1024 + k)
                                  : (hprev + (size_t)m * 1024 + (k - 1024));
    float4 f0 = *(const float4*)src;
    float4 f1 = *(const float4*)(src + 4);
    v[0]=f0.x; v[1]=f0.y; v[2]=f0.z; v[3]=f0.w;
    v[4]=f1.x; v[5]=f1.y; v[6]=f1.z; v[7]=f1.w;
    float lm = 0.f;
    #pragma unroll
    for (int j = 0; j < 8; ++j) lm = fmaxf(lm, fabsf(v[j]));
    #pragma unroll
    for (int mask = 32; mask >= 1; mask >>= 1)
      lm = fmaxf(lm, __shfl_xor(lm, mask, 64));
    const int wave = t >> 6, lane = t & 63;
    if (lane == 0) wm[wave] = lm;
    __syncthreads();
    float rowmax = fmaxf(fmaxf(wm[0], wm[1]), fmaxf(wm[2], wm[3]));
    rowmax = fmaxf(rowmax, 1e-20f);
    if (t == 0) sA[m] = rowmax * (1.0f / 127.0f);
    const float qs = 127.0f / rowmax;
    uint32_t lo = 0, hi = 0;
    #pragma unroll
    for (int j = 0; j < 4; ++j) {
      int q = __float2int_rn(v[j] * qs);
      lo |= (uint32_t)(q & 255) << (8 * j);
    }
    #pragma unroll
    for (int j = 0; j < 4; ++j) {
      int q = __float2int_rn(v[4 + j] * qs);
      hi |= (uint32_t)(q & 255) << (8 * j);
    }
    uint2 out; out.x = lo; out.y = hi;
    *(uint2*)(Ai8 + (size_t)m * D_K + k) = out;
  } else {
    const int n = r - B_SZ;
    const int g = n >> 10, h = n & 1023;
    const float* wsrc = (g == 0) ? Wi : (g == 1) ? Wf : (g == 2) ? Wc : Wo;
    const float* src = wsrc + (size_t)h * D_K + k;
    float4 f0 = *(const float4*)src;
    float4 f1 = *(const float4*)(src + 4);
    v[0]=f0.x; v[1]=f0.y; v[2]=f0.z; v[3]=f0.w;
    v[4]=f1.x; v[5]=f1.y; v[6]=f1.z; v[7]=f1.w;
    const float qs = 127.0f * SQRT2048;   // 127/s
    uint32_t lo = 0, hi = 0;
    #pragma unroll
    for (int j = 0; j < 4; ++j) {
      int q = min(127, max(-127, __float2int_rn(v[j] * qs)));
      lo |= (uint32_t)(q & 255) << (8 * j);
    }
    #pragma unroll
    for (int j = 0; j < 4; ++j) {
      int q = min(127, max(-127, __float2int_rn(v[4 + j] * qs)));
      hi |= (uint32_t)(q & 255) << (8 * j);
    }
    uint2 out; out.x = lo; out.y = hi;
    *(uint2*)(Wq8 + (size_t)n * D_K + k) = out;
  }
}

// Fused i8 GEMM + LSTM epilogue — 8-phase fine-interleaved schedule
// (m201 template ported to i8; R5's coarse split was the m196 anti-pattern).
//  * Block 256M x 256N (4 gates x 64 h), 512 thr = 8 waves (2M x 4N).
//    Wave tile 128M x (4 gates x 16h) = 8 Mfrags x 4 gate-frags, 16x16x64_i8,
//    acc = 8x4x4 = 128 i32 regs (exact accumulation).
//  * LDS: 2dbuf x (32KB A + 32KB B) = 128 KB -> 1 block/CU, 2 waves/SIMD.
//  * K-tile (BKI=128) = 4 phases. Phase p: {ds_read A-subtile (Mfrags 2p,2p+1;
//    B-frags read once at p==0 and HELD in regs) || issue part of next tile's
//    stage (A at p==0, B at p==1) -> barrier -> lgkmcnt(0) -> setprio(1),
//    16 MFMA, setprio(0) -> barrier}. vmem wait ONLY at p==3 (once per tile),
//    2-3 phases after issue -> latency hidden, no mid-tile drain.
// Bank swizzle (harness-verified): row r's logical 16B chunk c at physical
// c^(r&7); staging permutes the global SOURCE chunk (HW forces LDS dst =
// wavebase + lane*16; dOff = base + lane*16 exactly). The k-permutation
// cancels between identically-laid-out A and B; C/D layout dtype-independent.
__global__ __launch_bounds__(512, 1) void lstm_gemm_i8(
    const int8_t* __restrict__ A,   // [4096][2048] i8
    const int8_t* __restrict__ W,   // [4096][2048] i8 gate-major
    const float* __restrict__ sA,   // [4096] per-row A scale
    const float* __restrict__ bi, const float* __restrict__ bfv,
    const float* __restrict__ bc, const float* __restrict__ bo,
    const float* __restrict__ cprev,
    float* __restrict__ out)        // [h_next | c_next] fp32
{
  __shared__ __align__(16) int8_t lA[2][BM * BKI];    // 2 x 32 KB
  __shared__ __align__(16) int8_t lB[2][256 * BKI];   // 2 x 32 KB

  const int m0 = blockIdx.x * BM;
  const int h0 = blockIdx.y * BN_H;
  const int tid = threadIdx.x;
  const int wave = tid >> 6;   // 0..7
  const int lane = tid & 63;
  const int wm = wave >> 2;    // M half (128 rows)
  const int wn = wave & 3;     // 16-h slice

  // ---- staging: one instr = 64 lanes x 16B = 8 rows of 128B
  const int sr8 = lane >> 3;          // row within 8-row group
  const int sch = lane & 7;           // physical 16B chunk (forced by HW)
  const int gc  = sch ^ sr8;          // swizzled global source chunk (key=row&7)

  // A tile: 256 rows; 8 waves x 4 instrs x 8 rows. B tile: 256 rows, same split.
  const int8_t* aSrc[4];
  const int8_t* bSrc[4];
  int dOff[4];
  #pragma unroll
  for (int j = 0; j < 4; ++j) {
    int r = wave * 32 + j * 8 + sr8;            // 0..255, r&7 == sr8
    aSrc[j] = A + (size_t)(m0 + r) * D_K + gc * 16;
    // B LDS layout [gate][64 h']: row r -> gate r>>6, h' = r&63
    bSrc[j] = W + (size_t)((r >> 6) * DH + h0 + (r & 63)) * D_K + gc * 16;
    dOff[j] = r * BKI + sch * 16;               // = wavebase + lane*16
  }

  intx4 acc[8][4];
  #pragma unroll
  for (int i = 0; i < 8; ++i)
    #pragma unroll
    for (int j = 0; j < 4; ++j)
      acc[i][j] = (intx4){0, 0, 0, 0};

  // ---- fragment reads: frag row = base + fr; logical chunk kk*4+q
  const int fr = lane & 15;
  const int q  = lane >> 4;
  const int cx0 = ((q + 0) ^ (fr & 7)) * 16;   // kk=0
  const int cx1 = ((q + 4) ^ (fr & 7)) * 16;   // kk=1

#define STAGE_A(buf, kt) do {                                                \
    const int _ko = (kt) * BKI;                                              \
    _Pragma("unroll")                                                        \
    for (int j = 0; j < 4; ++j)                                              \
      __builtin_amdgcn_global_load_lds(                                      \
          (const __attribute__((address_space(1))) void*)(aSrc[j] + _ko),    \
          (__attribute__((address_space(3))) void*)&lA[buf][dOff[j]], 16, 0, 0); \
  } while (0)

#define STAGE_B(buf, kt) do {                                                \
    const int _ko = (kt) * BKI;                                              \
    _Pragma("unroll")                                                        \
    for (int j = 0; j < 4; ++j)                                              \
      __builtin_amdgcn_global_load_lds(                                      \
          (const __attribute__((address_space(1))) void*)(bSrc[j] + _ko),    \
          (__attribute__((address_space(3))) void*)&lB[buf][dOff[j]], 16, 0, 0); \
  } while (0)

  // Prologue: stage tile 0 fully, drain, barrier.
  STAGE_A(0, 0);
  STAGE_B(0, 0);
  asm volatile("s_waitcnt vmcnt(0)" ::: "memory");
  __builtin_amdgcn_s_barrier();

  #pragma unroll 1
  for (int t = 0; t < NIT; ++t) {
    const int b = t & 1;
    intx4 bq[4][2];   // 4 gate-frags x 2 kk, held across the tile's 4 phases

    #pragma unroll
    for (int p = 0; p < 4; ++p) {
      // ---- region A: ds_reads for this phase + partial next-tile stage
      if (p == 0) {
        #pragma unroll
        for (int g = 0; g < 4; ++g) {
          const int rb = (g * 64 + wn * 16 + fr) * BKI;
          bq[g][0] = *(const intx4*)&lB[b][rb + cx0];
          bq[g][1] = *(const intx4*)&lB[b][rb + cx1];
        }
      }
      intx4 aq[2][2];
      #pragma unroll
      for (int s = 0; s < 2; ++s) {
        const int ra = (wm * 128 + (2 * p + s) * 16 + fr) * BKI;
        aq[s][0] = *(const intx4*)&lA[b][ra + cx0];
        aq[s][1] = *(const intx4*)&lA[b][ra + cx1];
      }
      if (p == 0 && t + 1 < NIT) STAGE_A(b ^ 1, t + 1);
      if (p == 1 && t + 1 < NIT) STAGE_B(b ^ 1, t + 1);

      asm volatile("" ::: "memory");
      __builtin_amdgcn_s_barrier();
      asm volatile("s_waitcnt lgkmcnt(0)" ::: "memory");

      // ---- MFMA cluster: 16 MFMAs (Mfrags 2p,2p+1 x 4 gates x 2 kk)
      __builtin_amdgcn_s_setprio(1);
      #pragma unroll
      for (int kk = 0; kk < 2; ++kk)
        #pragma unroll
        for (int s = 0; s < 2; ++s)
          #pragma unroll
          for (int g = 0; g < 4; ++g)
            acc[2 * p + s][g] = __builtin_amdgcn_mfma_i32_16x16x64_i8(
                aq[s][kk], bq[g][kk], acc[2 * p + s][g], 0, 0, 0);
      __builtin_amdgcn_s_setprio(0);

      // ---- tile boundary: next tile's loads (issued at p0/p1) must land.
      if (p == 3) asm volatile("s_waitcnt vmcnt(0)" ::: "memory");
      asm volatile("" ::: "memory");
      __builtin_amdgcn_s_barrier();
    }
  }

#undef STAGE_A
#undef STAGE_B

  // Epilogue: C/D layout col=lane&15, row=(lane>>4)*4+reg (dtype-independent).
  // z = acc_i32 * (sA[m] * s/127) + bias
  const int col = lane & 15;
  const int rq = lane >> 4;
  const int h = h0 + wn * 16 + col;
  const float sWc = (1.0f / SQRT2048) * (1.0f / 127.0f);   // s/127
  const float bias_i = bi[h], bias_f = bfv[h], bias_c = bc[h], bias_o = bo[h];
  float* hout = out;
  float* cout = out + (size_t)B_SZ * DH;
  #pragma unroll
  for (int mf = 0; mf < 8; ++mf) {
    int mb = m0 + wm * 128 + mf * 16 + rq * 4;
    #pragma unroll
    for (int r = 0; r < 4; ++r) {
      int m = mb + r;
      float fz = sA[m] * sWc;
      float zi = (float)acc[mf][0][r] * fz + bias_i;
      float zf = (float)acc[mf][1][r] * fz + bias_f;
      float zc = (float)acc[mf][2][r] * fz + bias_c;
      float zo = (float)acc[mf][3][r] * fz + bias_o;
      float ig = fast_sigmoid(zi);
      float fg = fast_sigmoid(zf);
      float cg = fast_tanh(zc);
      float og = fast_sigmoid(zo);
      float cp = cprev[(size_t)m * DH + h];
      float cn = fg * cp + ig * cg;
      float hn = og * fast_tanh(cn);
      hout[(size_t)m * DH + h] = hn;
      cout[(size_t)m * DH + h] = cn;
    }
  }
}

extern "C" void kernel_launch(void* const* d_in, const int* in_sizes, int n_in,
                              void* d_out, int out_size, void* d_ws, size_t ws_size,
                              hipStream_t stream)
{
  const float* xin   = (const float*)d_in[0];
  const float* hprev = (const float*)d_in[1];
  const float* cprev = (const float*)d_in[2];
  const float* Wi    = (const float*)d_in[3];
  const float* bi    = (const float*)d_in[4];
  const float* Wf    = (const float*)d_in[5];
  const float* bfv   = (const float*)d_in[6];
  const float* Wc    = (const float*)d_in[7];
  const float* bc    = (const float*)d_in[8];
  const float* Wo    = (const float*)d_in[9];
  const float* bo    = (const float*)d_in[10];
  float* out = (float*)d_out;

  int8_t* Ai8 = (int8_t*)d_ws;                                 // 8 MB
  int8_t* Wq8 = Ai8 + (size_t)B_SZ * D_K;                      // 8 MB
  float*  sA  = (float*)(Wq8 + (size_t)4 * DH * D_K);          // 16 KB

  prep_i8<<<2 * B_SZ, 256, 0, stream>>>(
      xin, hprev, Wi, Wf, Wc, Wo, Ai8, Wq8, sA);

  dim3 grid(B_SZ / BM, DH / BN_H);  // 16 x 16 = 256 blocks (1/CU)
  lstm_gemm_i8<<<grid, 512, 0, stream>>>(
      Ai8, Wq8, sA, bi, bfv, bc, bo, cprev, out);
}